// Round 12
// baseline (379.046 us; speedup 1.0000x reference)
//
#include <hip/hip_runtime.h>
#include <hip/hip_bf16.h>
#include <stdint.h>

typedef unsigned short u16;
typedef __attribute__((ext_vector_type(4))) float f32x4;
typedef __attribute__((ext_vector_type(8))) short s16x8;

#define SEQ 2048
#define NB 4
#define DM 1024
#define NHD 16
#define DH 64

__device__ __forceinline__ u16 f2bf(float f) {
  union { float f; uint32_t u; } v; v.f = f;
  return (u16)((v.u + 0x7FFFu + ((v.u >> 16) & 1u)) >> 16);
}
__device__ __forceinline__ float bf2f(u16 u) {
  union { uint32_t u; float f; } v; v.u = ((uint32_t)u) << 16;
  return v.f;
}
// async global->LDS, 16B/lane; LDS dest = wave-uniform base + lane*16
__device__ __forceinline__ void gload16(const u16* g, u16* l) {
  __builtin_amdgcn_global_load_lds((const __attribute__((address_space(1))) void*)g,
                                   (__attribute__((address_space(3))) void*)l, 16, 0, 0);
}

// ---- stage a 64x64 bf16 tile into XOR-swizzled LDS (8-wave / 512-thr version) ----
__device__ __forceinline__ void stage64x64_swz8(const u16* gbase, long gstride,
                                                u16* lds, int tid) {
  int l = tid & 63, w = tid >> 6;          // w in 0..7
  int rsub = l >> 3;
  int srcElem = ((l & 7) ^ rsub) * 8;
  int row0 = w * 8;                        // wave-uniform LDS base row
  gload16(gbase + (long)(row0 + rsub) * gstride + srcElem, lds + row0 * 64);
}
__device__ __forceinline__ s16x8 frag_swz(const u16* lds, int row, int cb) {
  return *(const s16x8*)&lds[row * 64 + (cb ^ ((row & 7) << 3))];
}

// ---------- fused prologue: cvt + trig LUT + both weight transposes ----------
__device__ __forceinline__ void tpose_dev(const float* __restrict__ in,
                                          u16* __restrict__ out, int R, int C,
                                          int bx, int by, int tid) {
  __shared__ u16 tile[64][65];
  int c0 = bx * 64, r0 = by * 64;
  int tx = tid & 63, ty = tid >> 6;
  #pragma unroll
  for (int rr = ty; rr < 64; rr += 4)
    tile[rr][tx] = f2bf(in[(long)(r0 + rr) * C + c0 + tx]);
  __syncthreads();
  #pragma unroll
  for (int cc = ty; cc < 64; cc += 4)
    out[(long)(c0 + cc) * R + r0 + tx] = tile[tx][cc];
}

__global__ __launch_bounds__(256) void k_prep(const float* __restrict__ x,
                                              const float* __restrict__ w_qkv,
                                              const float* __restrict__ w_out,
                                              u16* __restrict__ Xb,
                                              float2* __restrict__ cs,
                                              u16* __restrict__ WqT,
                                              u16* __restrict__ WoT) {
  int bid = blockIdx.x, tid = threadIdx.x;
  if (bid < 1024) {
    // fp32 -> bf16 convert of x (grid-stride over 2,097,152 float4s)
    const int n4 = (NB * SEQ * DM) / 4;
    for (int idx = bid * 256 + tid; idx < n4; idx += 1024 * 256) {
      float4 v = ((const float4*)x)[idx];
      ushort4 o;
      o.x = f2bf(v.x); o.y = f2bf(v.y); o.z = f2bf(v.z); o.w = f2bf(v.w);
      ((ushort4*)Xb)[idx] = o;
    }
  } else if (bid < 1280) {
    // cos/sin LUT: cs[s*32+i]
    int t = (bid - 1024) * 256 + tid;
    int s = t >> 5, ih = t & 31;
    float fq = exp2f(-(float)ih * 0.4152410118609203f);  // 10000^(-ih/32)
    float ang = (float)s * fq;
    cs[t] = make_float2(cosf(ang), sinf(ang));
  } else if (bid < 2048) {
    // w_qkv [1024][3072] -> WqT [3072][1024]
    int id = bid - 1280;                   // 0..767
    tpose_dev(w_qkv, WqT, DM, 3 * DM, id % 48, id / 48, tid);
  } else {
    // w_out [1024][1024] -> WoT
    int id = bid - 2048;                   // 0..255
    tpose_dev(w_out, WoT, DM, DM, id % 16, id / 16, tid);
  }
}

// ---------- fused QKV GEMM: qkv = x@WqT + b, RoPE(LUT)/scale/layout epilogue ----------
// Round-8 proven structure: 128x128 tile, BK=64, 4 waves 2x2, two barriers/K-step.
__global__ __launch_bounds__(256) void k_gemm_qkv(const u16* __restrict__ A,
                                                  const u16* __restrict__ Bt,
                                                  const float* __restrict__ bias,
                                                  const float2* __restrict__ cs,
                                                  u16* __restrict__ Qr,
                                                  u16* __restrict__ Kr,
                                                  u16* __restrict__ VtG) {
  const int K = DM;
  __shared__ u16 As[128 * 64];
  __shared__ u16 Bs[128 * 64];
  int tid = threadIdx.x, lane = tid & 63, wave = tid >> 6;
  int wm = (wave >> 1) * 64, wn = (wave & 1) * 64;
  long m0 = (long)blockIdx.y * 128, n0 = (long)blockIdx.x * 128;
  int lrow = lane & 15, lk8 = (lane >> 4) * 8;
  int srow = wave * 8 + (lane >> 3);
  int scol = (lane & 7) * 8;
  const u16* Ag = &A[(m0 + srow) * (long)K + scol];
  const u16* Bg = &Bt[(n0 + srow) * (long)K + scol];
  f32x4 acc[4][4] = {};
  for (int k0 = 0; k0 < K; k0 += 64) {
    __syncthreads();
    #pragma unroll
    for (int p = 0; p < 4; ++p) {
      gload16(Ag + (long)p * 32 * K + k0, &As[(p * 32 + wave * 8) * 64]);
      gload16(Bg + (long)p * 32 * K + k0, &Bs[(p * 32 + wave * 8) * 64]);
    }
    __syncthreads();
    #pragma unroll
    for (int h = 0; h < 2; ++h) {
      s16x8 af[4], bfr[4];
      #pragma unroll
      for (int t = 0; t < 4; ++t)
        af[t]  = *(const s16x8*)&As[(wm + t * 16 + lrow) * 64 + h * 32 + lk8];
      #pragma unroll
      for (int t = 0; t < 4; ++t)
        bfr[t] = *(const s16x8*)&Bs[(wn + t * 16 + lrow) * 64 + h * 32 + lk8];
      #pragma unroll
      for (int i = 0; i < 4; ++i)
        #pragma unroll
        for (int j = 0; j < 4; ++j)
          acc[i][j] = __builtin_amdgcn_mfma_f32_16x16x32_bf16(af[i], bfr[j], acc[i][j], 0, 0, 0);
    }
  }
  // ---- epilogue: section routing; wave's 64-col span = exactly one head ----
  int coln = (int)(n0) + wn;
  int sec = coln >> 10;                    // 0=q, 1=k, 2=v
  int hh = (coln & 1023) >> 6;
  int crow = (lane >> 4) * 4, ccol = lane & 15;
  int rowb = (int)m0 + wm;
  if (sec < 2) {
    u16* dst = (sec == 0) ? Qr : Kr;
    float sc = (sec == 0) ? 0.125f : 1.0f;
    #pragma unroll
    for (int j2 = 0; j2 < 2; ++j2) {
      int ih = j2 * 16 + ccol;
      float bv1 = bias[coln + j2 * 16 + ccol];
      float bv2 = bias[coln + j2 * 16 + ccol + 32];
      #pragma unroll
      for (int i = 0; i < 4; ++i) {
        #pragma unroll
        for (int r = 0; r < 4; ++r) {
          int row = rowb + i * 16 + crow + r;
          int b = row >> 11, s = row & 2047;
          float2 cv = cs[(s << 5) + ih];
          float v1 = acc[i][j2][r] + bv1;
          float v2 = acc[i][j2 + 2][r] + bv2;
          long ob = ((long)((b * NHD + hh) * SEQ + s)) * 64;
          dst[ob + ih]      = f2bf((v1 * cv.x - v2 * cv.y) * sc);
          dst[ob + ih + 32] = f2bf((v2 * cv.x + v1 * cv.y) * sc);
        }
      }
    }
  } else {
    #pragma unroll
    for (int i = 0; i < 4; ++i) {
      int row = rowb + i * 16 + crow;
      int b = row >> 11, sl = row & 2047;
      int jt = sl >> 6, sr = sl & 63;
      #pragma unroll
      for (int j = 0; j < 4; ++j) {
        int d = j * 16 + ccol;
        float bv = bias[coln + j * 16 + ccol];
        long idx = (((long)(b * NHD + hh) * 32 + jt) * 64 + d) * 64 + sr;
        ushort4 o;
        o.x = f2bf(acc[i][j][0] + bv); o.y = f2bf(acc[i][j][1] + bv);
        o.z = f2bf(acc[i][j][2] + bv); o.w = f2bf(acc[i][j][3] + bv);
        *(ushort4*)&VtG[idx] = o;
      }
    }
  }
}

// ---------- bf16 GEMM via global_load_lds, BK=64 (out-projection; round-8 proven) ----------
template<int OUT_BF16>
__global__ __launch_bounds__(256) void k_gemm(const u16* __restrict__ A,
                                              const u16* __restrict__ Bt_g,
                                              const float* __restrict__ bias,
                                              void* __restrict__ Cout,
                                              int M, int N, int K) {
  __shared__ u16 As[128 * 64];
  __shared__ u16 Bs[128 * 64];
  int tid = threadIdx.x, lane = tid & 63, wave = tid >> 6;
  int wm = (wave >> 1) * 64, wn = (wave & 1) * 64;
  long m0 = (long)blockIdx.y * 128, n0 = (long)blockIdx.x * 128;
  int lrow = lane & 15, lk8 = (lane >> 4) * 8;
  int srow = wave * 8 + (lane >> 3);
  int scol = (lane & 7) * 8;
  const u16* Ag = &A[(m0 + srow) * (long)K + scol];
  const u16* Bg = &Bt_g[(n0 + srow) * (long)K + scol];
  f32x4 acc[4][4] = {};
  for (int k0 = 0; k0 < K; k0 += 64) {
    __syncthreads();
    #pragma unroll
    for (int p = 0; p < 4; ++p) {
      gload16(Ag + (long)p * 32 * K + k0, &As[(p * 32 + wave * 8) * 64]);
      gload16(Bg + (long)p * 32 * K + k0, &Bs[(p * 32 + wave * 8) * 64]);
    }
    __syncthreads();
    #pragma unroll
    for (int h = 0; h < 2; ++h) {
      s16x8 af[4], bfr[4];
      #pragma unroll
      for (int t = 0; t < 4; ++t)
        af[t]  = *(const s16x8*)&As[(wm + t * 16 + lrow) * 64 + h * 32 + lk8];
      #pragma unroll
      for (int t = 0; t < 4; ++t)
        bfr[t] = *(const s16x8*)&Bs[(wn + t * 16 + lrow) * 64 + h * 32 + lk8];
      #pragma unroll
      for (int i = 0; i < 4; ++i)
        #pragma unroll
        for (int j = 0; j < 4; ++j)
          acc[i][j] = __builtin_amdgcn_mfma_f32_16x16x32_bf16(af[i], bfr[j], acc[i][j], 0, 0, 0);
    }
  }
  int crow = (lane >> 4) * 4, ccol = lane & 15;
  #pragma unroll
  for (int i = 0; i < 4; ++i)
  #pragma unroll
  for (int j = 0; j < 4; ++j) {
    long col = n0 + wn + j * 16 + ccol;
    float bv = bias ? bias[col] : 0.f;
    #pragma unroll
    for (int r = 0; r < 4; ++r) {
      long row = m0 + wm + i * 16 + crow + r;
      float v = acc[i][j][r] + bv;
      if (OUT_BF16) ((u16*)Cout)[row * N + col] = f2bf(v);
      else          ((float*)Cout)[row * N + col] = v;
    }
  }
}

// ---------- causal attention: QBLK=128, 8 waves, sweep1 K-dbuf, XCD-pinned, T5 setprio ----------
__global__ __launch_bounds__(512) void k_attn(const u16* __restrict__ Qr,
                                              const u16* __restrict__ Kr,
                                              const u16* __restrict__ VtG,
                                              float* __restrict__ attn,
                                              u16* __restrict__ ctx) {
  constexpr int LP = 72;
  __shared__ u16 Ks[64 * 64];
  __shared__ u16 Vs[64 * 64];
  __shared__ u16 Ps[8][16 * LP];
  int tid = threadIdx.x, lane = tid & 63, wave = tid >> 6;   // wave 0..7
  // XCD-pin: all 16 q-blocks of a bh share one XCD class; big-qb first (LPT).
  int wgid = blockIdx.x;                   // 0..1023
  int c = wgid & 7, t7 = wgid >> 3;        // t7 0..127
  int bh = c * 8 + (t7 >> 4);
  int qb = 15 - (t7 & 15);
  int q0 = qb * 128;
  int qw0 = q0 + wave * 16;
  int lrow = lane & 15, lg = lane >> 4, lk8 = (lane >> 4) * 8;
  const u16* Qb = Qr + (long)bh * SEQ * 64;
  const u16* Kb = Kr + (long)bh * SEQ * 64;
  const u16* Vtb = VtG + (long)bh * 32 * 4096;
  float* attn_bh = attn + (long)bh * SEQ * SEQ;

  s16x8 qf0 = *(const s16x8*)&Qb[(long)(qw0 + lrow) * 64 + lk8];
  s16x8 qf1 = *(const s16x8*)&Qb[(long)(qw0 + lrow) * 64 + 32 + lk8];

  int njt = 2 * qb + 2;                    // causal k-tiles (64-wide)

  // ---- sweep 1: row sums of exp(score); K double-buffered across Ks/Vs ----
  float suml[4] = {0.f, 0.f, 0.f, 0.f};
  stage64x64_swz8(Kb, 64, Ks, tid);
  __syncthreads();
  for (int jt = 0; jt < njt; ++jt) {
    const u16* cur = (jt & 1) ? Vs : Ks;
    u16* nxt = (jt & 1) ? Ks : Vs;
    if (jt + 1 < njt)
      stage64x64_swz8(Kb + (long)(jt + 1) * 64 * 64, 64, nxt, tid);
    int dt2 = jt - 2 * qb;                 // <0 interior; 0/1 = diagonal tiles
    int wq = (dt2 < 0) ? 100 : (wave - 4 * dt2);
    int ctmax = (wq < 3) ? wq : 3;
    long k0 = (long)jt * 64;
    for (int ct = 0; ct <= ctmax; ++ct) {
      int row = ct * 16 + lrow;
      s16x8 kf0 = frag_swz(cur, row, lk8);
      s16x8 kf1 = frag_swz(cur, row, 32 + lk8);
      f32x4 sa = {0.f, 0.f, 0.f, 0.f};
      __builtin_amdgcn_s_setprio(1);       // T5: favor MFMA-issuing wave
      sa = __builtin_amdgcn_mfma_f32_16x16x32_bf16(qf0, kf0, sa, 0, 0, 0);
      sa = __builtin_amdgcn_mfma_f32_16x16x32_bf16(qf1, kf1, sa, 0, 0, 0);
      __builtin_amdgcn_s_setprio(0);
      bool diag = (ct == wq);
      int gcol = (int)k0 + ct * 16 + lrow;
      #pragma unroll
      for (int r = 0; r < 4; ++r) {
        int grow = qw0 + lg * 4 + r;
        float e = (!diag || gcol <= grow) ? __expf(sa[r]) : 0.f;
        suml[r] += e;
      }
    }
    __syncthreads();
  }
  #pragma unroll
  for (int r = 0; r < 4; ++r) {
    float v = suml[r];
    v += __shfl_xor(v, 1, 16);
    v += __shfl_xor(v, 2, 16);
    v += __shfl_xor(v, 4, 16);
    v += __shfl_xor(v, 8, 16);
    suml[r] = 1.0f / v;
  }

  // ---- sweep 2: probs -> Ps -> PV MFMA -> coalesced nt attn write ----
  f32x4 oacc[4] = {};
  u16* ps = &Ps[wave][0];
  for (int jt = 0; jt < njt; ++jt) {
    __syncthreads();
    stage64x64_swz8(Kb + (long)jt * 64 * 64, 64, Ks, tid);
    stage64x64_swz8(Vtb + jt * 4096, 64, Vs, tid);
    __syncthreads();
    int dt2 = jt - 2 * qb;
    int wq = (dt2 < 0) ? 100 : (wave - 4 * dt2);
    int ctmax = (wq < 3) ? wq : 3;
    long k0 = (long)jt * 64;
    #pragma unroll
    for (int ct = 0; ct < 4; ++ct) {
      if (ct <= ctmax) {
        int row = ct * 16 + lrow;
        s16x8 kf0 = frag_swz(Ks, row, lk8);
        s16x8 kf1 = frag_swz(Ks, row, 32 + lk8);
        f32x4 sa = {0.f, 0.f, 0.f, 0.f};
        __builtin_amdgcn_s_setprio(1);     // T5
        sa = __builtin_amdgcn_mfma_f32_16x16x32_bf16(qf0, kf0, sa, 0, 0, 0);
        sa = __builtin_amdgcn_mfma_f32_16x16x32_bf16(qf1, kf1, sa, 0, 0, 0);
        __builtin_amdgcn_s_setprio(0);
        bool diag = (ct == wq);
        int gcol = (int)k0 + ct * 16 + lrow;
        #pragma unroll
        for (int r = 0; r < 4; ++r) {
          int grow = qw0 + lg * 4 + r;
          float e = (!diag || gcol <= grow) ? __expf(sa[r]) : 0.f;
          ps[(lg * 4 + r) * LP + ct * 16 + lrow] = f2bf(e * suml[r]);
        }
      } else {
        #pragma unroll
        for (int r = 0; r < 4; ++r)
          ps[(lg * 4 + r) * LP + ct * 16 + lrow] = 0;
      }
    }
    // PV: O += P @ V
    s16x8 pf0 = *(const s16x8*)&ps[lrow * LP + lk8];
    s16x8 pf1 = *(const s16x8*)&ps[lrow * LP + 32 + lk8];
    __builtin_amdgcn_s_setprio(1);         // T5: PV MFMA cluster
    #pragma unroll
    for (int dt = 0; dt < 4; ++dt) {
      int row = dt * 16 + lrow;
      s16x8 vf0 = frag_swz(Vs, row, lk8);
      s16x8 vf1 = frag_swz(Vs, row, 32 + lk8);
      oacc[dt] = __builtin_amdgcn_mfma_f32_16x16x32_bf16(pf0, vf0, oacc[dt], 0, 0, 0);
      oacc[dt] = __builtin_amdgcn_mfma_f32_16x16x32_bf16(pf1, vf1, oacc[dt], 0, 0, 0);
    }
    __builtin_amdgcn_s_setprio(0);
    // coalesced nt attn write: 16 lanes cover one row's 64B segment
    #pragma unroll
    for (int it = 0; it < 4; ++it) {
      int prow = it * 4 + (lane >> 4);
      int c4 = lane & 15;
      ushort4 pv = *(const ushort4*)&ps[prow * LP + c4 * 4];
      f32x4 o;
      o.x = bf2f(pv.x); o.y = bf2f(pv.y); o.z = bf2f(pv.z); o.w = bf2f(pv.w);
      __builtin_nontemporal_store(o,
          (f32x4*)&attn_bh[(long)(qw0 + prow) * SEQ + k0 + c4 * 4]);
    }
  }

  // ---- zero-fill columns beyond the q-block (nt stores), 128 rows ----
  {
    int cstart = q0 + 128;
    int zc4 = (SEQ - cstart) >> 2;
    f32x4 z = {0.f, 0.f, 0.f, 0.f};
    for (int row = 0; row < 128; ++row) {
      f32x4* dst = (f32x4*)&attn_bh[(long)(q0 + row) * SEQ + cstart];
      for (int cc = tid; cc < zc4; cc += 512)
        __builtin_nontemporal_store(z, &dst[cc]);
    }
  }

  // ---- ctx write: [B*S][Dm] bf16 ----
  int b = bh >> 4, h = bh & 15;
  #pragma unroll
  for (int dt = 0; dt < 4; ++dt)
  #pragma unroll
  for (int r = 0; r < 4; ++r) {
    long grow = qw0 + lg * 4 + r;
    long col = h * 64 + dt * 16 + lrow;
    ctx[((long)b * SEQ + grow) * DM + col] = f2bf(oacc[dt][r]);
  }
}

extern "C" void kernel_launch(void* const* d_in, const int* in_sizes, int n_in,
                              void* d_out, int out_size, void* d_ws, size_t ws_size,
                              hipStream_t stream) {
  const float* x     = (const float*)d_in[0];
  const float* w_qkv = (const float*)d_in[1];
  const float* b_qkv = (const float*)d_in[2];
  const float* w_out = (const float*)d_in[3];
  const float* b_out = (const float*)d_in[4];
  float* outp = (float*)d_out;
  float* attn = outp + (long)NB * SEQ * DM;

  char* ws = (char*)d_ws;
  u16* Qr  = (u16*)(ws);                 // 16,777,216 B
  u16* Kr  = (u16*)(ws + 16777216L);     // 16,777,216 B
  u16* VtG = (u16*)(ws + 33554432L);     // 16,777,216 B
  u16* ctx = (u16*)(ws + 50331648L);     // 16,777,216 B
  u16* WoT = (u16*)(ws + 67108864L);     //  2,097,152 B

  // dead-before-k_attn scratch inside the attn output region (fully rewritten)
  u16*    Xb  = (u16*)attn;                           // bf16 x [8192][1024]
  u16*    WqT = (u16*)((char*)attn + 16777216L);      // w_qkv^T bf16 [3072][1024]
  float2* cst = (float2*)((char*)attn + 23068672L);   // cos/sin LUT 512KB

  // fused prologue: cvt + trig + both transposes in one launch
  k_prep<<<2304, 256, 0, stream>>>(x, w_qkv, w_out, Xb, cst, WqT, WoT);

  // fused: qkv GEMM + bias + RoPE(LUT)/scale + head layout + V transpose
  k_gemm_qkv<<<dim3(3 * DM / 128, NB * SEQ / 128), 256, 0, stream>>>(
      Xb, WqT, b_qkv, cst, Qr, Kr, VtG);

  k_attn<<<1024, 512, 0, stream>>>(Qr, Kr, VtG, attn, ctx);

  k_gemm<0><<<dim3(DM / 128, NB * SEQ / 128), 256, 0, stream>>>(
      ctx, WoT, b_out, outp, NB * SEQ, DM, DM);
}

// Round 13
// 367.821 us; speedup vs baseline: 1.0305x; 1.0305x over previous
//
#include <hip/hip_runtime.h>
#include <hip/hip_bf16.h>
#include <stdint.h>

typedef unsigned short u16;
typedef __attribute__((ext_vector_type(4))) float f32x4;
typedef __attribute__((ext_vector_type(8))) short s16x8;

#define SEQ 2048
#define NB 4
#define DM 1024
#define NHD 16
#define DH 64

__device__ __forceinline__ u16 f2bf(float f) {
  union { float f; uint32_t u; } v; v.f = f;
  return (u16)((v.u + 0x7FFFu + ((v.u >> 16) & 1u)) >> 16);
}
__device__ __forceinline__ float bf2f(u16 u) {
  union { uint32_t u; float f; } v; v.u = ((uint32_t)u) << 16;
  return v.f;
}
// async global->LDS, 16B/lane; LDS dest = wave-uniform base + lane*16
__device__ __forceinline__ void gload16(const u16* g, u16* l) {
  __builtin_amdgcn_global_load_lds((const __attribute__((address_space(1))) void*)g,
                                   (__attribute__((address_space(3))) void*)l, 16, 0, 0);
}

// ---- stage a 64x64 bf16 tile into XOR-swizzled LDS (8-wave / 512-thr version) ----
__device__ __forceinline__ void stage64x64_swz8(const u16* gbase, long gstride,
                                                u16* lds, int tid) {
  int l = tid & 63, w = tid >> 6;          // w in 0..7
  int rsub = l >> 3;
  int srcElem = ((l & 7) ^ rsub) * 8;
  int row0 = w * 8;                        // wave-uniform LDS base row
  gload16(gbase + (long)(row0 + rsub) * gstride + srcElem, lds + row0 * 64);
}
__device__ __forceinline__ s16x8 frag_swz(const u16* lds, int row, int cb) {
  return *(const s16x8*)&lds[row * 64 + (cb ^ ((row & 7) << 3))];
}

// ---------- fused prologue: cvt + trig LUT + both weight transposes ----------
__device__ __forceinline__ void tpose_dev(const float* __restrict__ in,
                                          u16* __restrict__ out, int R, int C,
                                          int bx, int by, int tid) {
  __shared__ u16 tile[64][65];
  int c0 = bx * 64, r0 = by * 64;
  int tx = tid & 63, ty = tid >> 6;
  #pragma unroll
  for (int rr = ty; rr < 64; rr += 4)
    tile[rr][tx] = f2bf(in[(long)(r0 + rr) * C + c0 + tx]);
  __syncthreads();
  #pragma unroll
  for (int cc = ty; cc < 64; cc += 4)
    out[(long)(c0 + cc) * R + r0 + tx] = tile[tx][cc];
}

__global__ __launch_bounds__(256) void k_prep(const float* __restrict__ x,
                                              const float* __restrict__ w_qkv,
                                              const float* __restrict__ w_out,
                                              u16* __restrict__ Xb,
                                              float2* __restrict__ cs,
                                              u16* __restrict__ WqT,
                                              u16* __restrict__ WoT) {
  int bid = blockIdx.x, tid = threadIdx.x;
  if (bid < 1024) {
    // fp32 -> bf16 convert of x (grid-stride over 2,097,152 float4s)
    const int n4 = (NB * SEQ * DM) / 4;
    for (int idx = bid * 256 + tid; idx < n4; idx += 1024 * 256) {
      float4 v = ((const float4*)x)[idx];
      ushort4 o;
      o.x = f2bf(v.x); o.y = f2bf(v.y); o.z = f2bf(v.z); o.w = f2bf(v.w);
      ((ushort4*)Xb)[idx] = o;
    }
  } else if (bid < 1280) {
    // cos/sin LUT: cs[s*32+i]
    int t = (bid - 1024) * 256 + tid;
    int s = t >> 5, ih = t & 31;
    float fq = exp2f(-(float)ih * 0.4152410118609203f);  // 10000^(-ih/32)
    float ang = (float)s * fq;
    cs[t] = make_float2(cosf(ang), sinf(ang));
  } else if (bid < 2048) {
    // w_qkv [1024][3072] -> WqT [3072][1024]
    int id = bid - 1280;                   // 0..767
    tpose_dev(w_qkv, WqT, DM, 3 * DM, id % 48, id / 48, tid);
  } else {
    // w_out [1024][1024] -> WoT
    int id = bid - 2048;                   // 0..255
    tpose_dev(w_out, WoT, DM, DM, id % 16, id / 16, tid);
  }
}

// ---------- fused QKV GEMM: qkv = x@WqT + b, RoPE(LUT)/scale/layout epilogue ----------
// Round-8 proven structure: 128x128 tile, BK=64, 4 waves 2x2, two barriers/K-step.
__global__ __launch_bounds__(256) void k_gemm_qkv(const u16* __restrict__ A,
                                                  const u16* __restrict__ Bt,
                                                  const float* __restrict__ bias,
                                                  const float2* __restrict__ cs,
                                                  u16* __restrict__ Qr,
                                                  u16* __restrict__ Kr,
                                                  u16* __restrict__ VtG) {
  const int K = DM;
  __shared__ u16 As[128 * 64];
  __shared__ u16 Bs[128 * 64];
  int tid = threadIdx.x, lane = tid & 63, wave = tid >> 6;
  int wm = (wave >> 1) * 64, wn = (wave & 1) * 64;
  long m0 = (long)blockIdx.y * 128, n0 = (long)blockIdx.x * 128;
  int lrow = lane & 15, lk8 = (lane >> 4) * 8;
  int srow = wave * 8 + (lane >> 3);
  int scol = (lane & 7) * 8;
  const u16* Ag = &A[(m0 + srow) * (long)K + scol];
  const u16* Bg = &Bt[(n0 + srow) * (long)K + scol];
  f32x4 acc[4][4] = {};
  for (int k0 = 0; k0 < K; k0 += 64) {
    __syncthreads();
    #pragma unroll
    for (int p = 0; p < 4; ++p) {
      gload16(Ag + (long)p * 32 * K + k0, &As[(p * 32 + wave * 8) * 64]);
      gload16(Bg + (long)p * 32 * K + k0, &Bs[(p * 32 + wave * 8) * 64]);
    }
    __syncthreads();
    #pragma unroll
    for (int h = 0; h < 2; ++h) {
      s16x8 af[4], bfr[4];
      #pragma unroll
      for (int t = 0; t < 4; ++t)
        af[t]  = *(const s16x8*)&As[(wm + t * 16 + lrow) * 64 + h * 32 + lk8];
      #pragma unroll
      for (int t = 0; t < 4; ++t)
        bfr[t] = *(const s16x8*)&Bs[(wn + t * 16 + lrow) * 64 + h * 32 + lk8];
      #pragma unroll
      for (int i = 0; i < 4; ++i)
        #pragma unroll
        for (int j = 0; j < 4; ++j)
          acc[i][j] = __builtin_amdgcn_mfma_f32_16x16x32_bf16(af[i], bfr[j], acc[i][j], 0, 0, 0);
    }
  }
  // ---- epilogue: section routing; wave's 64-col span = exactly one head ----
  int coln = (int)(n0) + wn;
  int sec = coln >> 10;                    // 0=q, 1=k, 2=v
  int hh = (coln & 1023) >> 6;
  int crow = (lane >> 4) * 4, ccol = lane & 15;
  int rowb = (int)m0 + wm;
  if (sec < 2) {
    u16* dst = (sec == 0) ? Qr : Kr;
    float sc = (sec == 0) ? 0.125f : 1.0f;
    #pragma unroll
    for (int j2 = 0; j2 < 2; ++j2) {
      int ih = j2 * 16 + ccol;
      float bv1 = bias[coln + j2 * 16 + ccol];
      float bv2 = bias[coln + j2 * 16 + ccol + 32];
      #pragma unroll
      for (int i = 0; i < 4; ++i) {
        #pragma unroll
        for (int r = 0; r < 4; ++r) {
          int row = rowb + i * 16 + crow + r;
          int b = row >> 11, s = row & 2047;
          float2 cv = cs[(s << 5) + ih];
          float v1 = acc[i][j2][r] + bv1;
          float v2 = acc[i][j2 + 2][r] + bv2;
          long ob = ((long)((b * NHD + hh) * SEQ + s)) * 64;
          dst[ob + ih]      = f2bf((v1 * cv.x - v2 * cv.y) * sc);
          dst[ob + ih + 32] = f2bf((v2 * cv.x + v1 * cv.y) * sc);
        }
      }
    }
  } else {
    #pragma unroll
    for (int i = 0; i < 4; ++i) {
      int row = rowb + i * 16 + crow;
      int b = row >> 11, sl = row & 2047;
      int jt = sl >> 6, sr = sl & 63;
      #pragma unroll
      for (int j = 0; j < 4; ++j) {
        int d = j * 16 + ccol;
        float bv = bias[coln + j * 16 + ccol];
        long idx = (((long)(b * NHD + hh) * 32 + jt) * 64 + d) * 64 + sr;
        ushort4 o;
        o.x = f2bf(acc[i][j][0] + bv); o.y = f2bf(acc[i][j][1] + bv);
        o.z = f2bf(acc[i][j][2] + bv); o.w = f2bf(acc[i][j][3] + bv);
        *(ushort4*)&VtG[idx] = o;
      }
    }
  }
}

// ---------- bf16 GEMM via global_load_lds, BK=64 (out-projection; round-8 proven) ----------
template<int OUT_BF16>
__global__ __launch_bounds__(256) void k_gemm(const u16* __restrict__ A,
                                              const u16* __restrict__ Bt_g,
                                              const float* __restrict__ bias,
                                              void* __restrict__ Cout,
                                              int M, int N, int K) {
  __shared__ u16 As[128 * 64];
  __shared__ u16 Bs[128 * 64];
  int tid = threadIdx.x, lane = tid & 63, wave = tid >> 6;
  int wm = (wave >> 1) * 64, wn = (wave & 1) * 64;
  long m0 = (long)blockIdx.y * 128, n0 = (long)blockIdx.x * 128;
  int lrow = lane & 15, lk8 = (lane >> 4) * 8;
  int srow = wave * 8 + (lane >> 3);
  int scol = (lane & 7) * 8;
  const u16* Ag = &A[(m0 + srow) * (long)K + scol];
  const u16* Bg = &Bt_g[(n0 + srow) * (long)K + scol];
  f32x4 acc[4][4] = {};
  for (int k0 = 0; k0 < K; k0 += 64) {
    __syncthreads();
    #pragma unroll
    for (int p = 0; p < 4; ++p) {
      gload16(Ag + (long)p * 32 * K + k0, &As[(p * 32 + wave * 8) * 64]);
      gload16(Bg + (long)p * 32 * K + k0, &Bs[(p * 32 + wave * 8) * 64]);
    }
    __syncthreads();
    #pragma unroll
    for (int h = 0; h < 2; ++h) {
      s16x8 af[4], bfr[4];
      #pragma unroll
      for (int t = 0; t < 4; ++t)
        af[t]  = *(const s16x8*)&As[(wm + t * 16 + lrow) * 64 + h * 32 + lk8];
      #pragma unroll
      for (int t = 0; t < 4; ++t)
        bfr[t] = *(const s16x8*)&Bs[(wn + t * 16 + lrow) * 64 + h * 32 + lk8];
      #pragma unroll
      for (int i = 0; i < 4; ++i)
        #pragma unroll
        for (int j = 0; j < 4; ++j)
          acc[i][j] = __builtin_amdgcn_mfma_f32_16x16x32_bf16(af[i], bfr[j], acc[i][j], 0, 0, 0);
    }
  }
  int crow = (lane >> 4) * 4, ccol = lane & 15;
  #pragma unroll
  for (int i = 0; i < 4; ++i)
  #pragma unroll
  for (int j = 0; j < 4; ++j) {
    long col = n0 + wn + j * 16 + ccol;
    float bv = bias ? bias[col] : 0.f;
    #pragma unroll
    for (int r = 0; r < 4; ++r) {
      long row = m0 + wm + i * 16 + crow + r;
      float v = acc[i][j][r] + bv;
      if (OUT_BF16) ((u16*)Cout)[row * N + col] = f2bf(v);
      else          ((float*)Cout)[row * N + col] = v;
    }
  }
}

// ---------- causal attention: QBLK=128, 8 waves, sweep1 K-dbuf, XCD-pinned ----------
__global__ __launch_bounds__(512) void k_attn(const u16* __restrict__ Qr,
                                              const u16* __restrict__ Kr,
                                              const u16* __restrict__ VtG,
                                              float* __restrict__ attn,
                                              u16* __restrict__ ctx) {
  constexpr int LP = 72;
  __shared__ u16 Ks[64 * 64];
  __shared__ u16 Vs[64 * 64];
  __shared__ u16 Ps[8][16 * LP];
  int tid = threadIdx.x, lane = tid & 63, wave = tid >> 6;   // wave 0..7
  // XCD-pin: all 16 q-blocks of a bh share one XCD class; big-qb first (LPT).
  int wgid = blockIdx.x;                   // 0..1023
  int c = wgid & 7, t7 = wgid >> 3;        // t7 0..127
  int bh = c * 8 + (t7 >> 4);
  int qb = 15 - (t7 & 15);
  int q0 = qb * 128;
  int qw0 = q0 + wave * 16;
  int lrow = lane & 15, lg = lane >> 4, lk8 = (lane >> 4) * 8;
  const u16* Qb = Qr + (long)bh * SEQ * 64;
  const u16* Kb = Kr + (long)bh * SEQ * 64;
  const u16* Vtb = VtG + (long)bh * 32 * 4096;
  float* attn_bh = attn + (long)bh * SEQ * SEQ;

  s16x8 qf0 = *(const s16x8*)&Qb[(long)(qw0 + lrow) * 64 + lk8];
  s16x8 qf1 = *(const s16x8*)&Qb[(long)(qw0 + lrow) * 64 + 32 + lk8];

  int njt = 2 * qb + 2;                    // causal k-tiles (64-wide)

  // ---- sweep 1: row sums of exp(score); K double-buffered across Ks/Vs ----
  float suml[4] = {0.f, 0.f, 0.f, 0.f};
  stage64x64_swz8(Kb, 64, Ks, tid);
  __syncthreads();
  for (int jt = 0; jt < njt; ++jt) {
    const u16* cur = (jt & 1) ? Vs : Ks;
    u16* nxt = (jt & 1) ? Ks : Vs;
    if (jt + 1 < njt)
      stage64x64_swz8(Kb + (long)(jt + 1) * 64 * 64, 64, nxt, tid);
    int dt2 = jt - 2 * qb;                 // <0 interior; 0/1 = diagonal tiles
    int wq = (dt2 < 0) ? 100 : (wave - 4 * dt2);
    int ctmax = (wq < 3) ? wq : 3;
    long k0 = (long)jt * 64;
    for (int ct = 0; ct <= ctmax; ++ct) {
      int row = ct * 16 + lrow;
      s16x8 kf0 = frag_swz(cur, row, lk8);
      s16x8 kf1 = frag_swz(cur, row, 32 + lk8);
      f32x4 sa = {0.f, 0.f, 0.f, 0.f};
      sa = __builtin_amdgcn_mfma_f32_16x16x32_bf16(qf0, kf0, sa, 0, 0, 0);
      sa = __builtin_amdgcn_mfma_f32_16x16x32_bf16(qf1, kf1, sa, 0, 0, 0);
      bool diag = (ct == wq);
      int gcol = (int)k0 + ct * 16 + lrow;
      #pragma unroll
      for (int r = 0; r < 4; ++r) {
        int grow = qw0 + lg * 4 + r;
        float e = (!diag || gcol <= grow) ? __expf(sa[r]) : 0.f;
        suml[r] += e;
      }
    }
    __syncthreads();
  }
  #pragma unroll
  for (int r = 0; r < 4; ++r) {
    float v = suml[r];
    v += __shfl_xor(v, 1, 16);
    v += __shfl_xor(v, 2, 16);
    v += __shfl_xor(v, 4, 16);
    v += __shfl_xor(v, 8, 16);
    suml[r] = 1.0f / v;
  }

  // ---- sweep 2: probs -> Ps -> PV MFMA -> coalesced nt attn write ----
  f32x4 oacc[4] = {};
  u16* ps = &Ps[wave][0];
  for (int jt = 0; jt < njt; ++jt) {
    __syncthreads();
    stage64x64_swz8(Kb + (long)jt * 64 * 64, 64, Ks, tid);
    stage64x64_swz8(Vtb + jt * 4096, 64, Vs, tid);
    __syncthreads();
    int dt2 = jt - 2 * qb;
    int wq = (dt2 < 0) ? 100 : (wave - 4 * dt2);
    int ctmax = (wq < 3) ? wq : 3;
    long k0 = (long)jt * 64;
    #pragma unroll
    for (int ct = 0; ct < 4; ++ct) {
      if (ct <= ctmax) {
        int row = ct * 16 + lrow;
        s16x8 kf0 = frag_swz(Ks, row, lk8);
        s16x8 kf1 = frag_swz(Ks, row, 32 + lk8);
        f32x4 sa = {0.f, 0.f, 0.f, 0.f};
        sa = __builtin_amdgcn_mfma_f32_16x16x32_bf16(qf0, kf0, sa, 0, 0, 0);
        sa = __builtin_amdgcn_mfma_f32_16x16x32_bf16(qf1, kf1, sa, 0, 0, 0);
        bool diag = (ct == wq);
        int gcol = (int)k0 + ct * 16 + lrow;
        #pragma unroll
        for (int r = 0; r < 4; ++r) {
          int grow = qw0 + lg * 4 + r;
          float e = (!diag || gcol <= grow) ? __expf(sa[r]) : 0.f;
          ps[(lg * 4 + r) * LP + ct * 16 + lrow] = f2bf(e * suml[r]);
        }
      } else {
        #pragma unroll
        for (int r = 0; r < 4; ++r)
          ps[(lg * 4 + r) * LP + ct * 16 + lrow] = 0;
      }
    }
    // PV: O += P @ V
    s16x8 pf0 = *(const s16x8*)&ps[lrow * LP + lk8];
    s16x8 pf1 = *(const s16x8*)&ps[lrow * LP + 32 + lk8];
    #pragma unroll
    for (int dt = 0; dt < 4; ++dt) {
      int row = dt * 16 + lrow;
      s16x8 vf0 = frag_swz(Vs, row, lk8);
      s16x8 vf1 = frag_swz(Vs, row, 32 + lk8);
      oacc[dt] = __builtin_amdgcn_mfma_f32_16x16x32_bf16(pf0, vf0, oacc[dt], 0, 0, 0);
      oacc[dt] = __builtin_amdgcn_mfma_f32_16x16x32_bf16(pf1, vf1, oacc[dt], 0, 0, 0);
    }
    // coalesced nt attn write: 16 lanes cover one row's 64B segment
    #pragma unroll
    for (int it = 0; it < 4; ++it) {
      int prow = it * 4 + (lane >> 4);
      int c4 = lane & 15;
      ushort4 pv = *(const ushort4*)&ps[prow * LP + c4 * 4];
      f32x4 o;
      o.x = bf2f(pv.x); o.y = bf2f(pv.y); o.z = bf2f(pv.z); o.w = bf2f(pv.w);
      __builtin_nontemporal_store(o,
          (f32x4*)&attn_bh[(long)(qw0 + prow) * SEQ + k0 + c4 * 4]);
    }
  }

  // ---- zero-fill columns beyond the q-block (nt stores), 128 rows ----
  {
    int cstart = q0 + 128;
    int zc4 = (SEQ - cstart) >> 2;
    f32x4 z = {0.f, 0.f, 0.f, 0.f};
    for (int row = 0; row < 128; ++row) {
      f32x4* dst = (f32x4*)&attn_bh[(long)(q0 + row) * SEQ + cstart];
      for (int cc = tid; cc < zc4; cc += 512)
        __builtin_nontemporal_store(z, &dst[cc]);
    }
  }

  // ---- ctx write: [B*S][Dm] bf16 ----
  int b = bh >> 4, h = bh & 15;
  #pragma unroll
  for (int dt = 0; dt < 4; ++dt)
  #pragma unroll
  for (int r = 0; r < 4; ++r) {
    long grow = qw0 + lg * 4 + r;
    long col = h * 64 + dt * 16 + lrow;
    ctx[((long)b * SEQ + grow) * DM + col] = f2bf(oacc[dt][r]);
  }
}

extern "C" void kernel_launch(void* const* d_in, const int* in_sizes, int n_in,
                              void* d_out, int out_size, void* d_ws, size_t ws_size,
                              hipStream_t stream) {
  const float* x     = (const float*)d_in[0];
  const float* w_qkv = (const float*)d_in[1];
  const float* b_qkv = (const float*)d_in[2];
  const float* w_out = (const float*)d_in[3];
  const float* b_out = (const float*)d_in[4];
  float* outp = (float*)d_out;
  float* attn = outp + (long)NB * SEQ * DM;

  char* ws = (char*)d_ws;
  u16* Qr  = (u16*)(ws);                 // 16,777,216 B
  u16* Kr  = (u16*)(ws + 16777216L);     // 16,777,216 B
  u16* VtG = (u16*)(ws + 33554432L);     // 16,777,216 B
  u16* ctx = (u16*)(ws + 50331648L);     // 16,777,216 B
  u16* WoT = (u16*)(ws + 67108864L);     //  2,097,152 B

  // dead-before-k_attn scratch inside the attn output region (fully rewritten)
  u16*    Xb  = (u16*)attn;                           // bf16 x [8192][1024]
  u16*    WqT = (u16*)((char*)attn + 16777216L);      // w_qkv^T bf16 [3072][1024]
  float2* cst = (float2*)((char*)attn + 23068672L);   // cos/sin LUT 512KB

  // fused prologue: cvt + trig + both transposes in one launch
  k_prep<<<2304, 256, 0, stream>>>(x, w_qkv, w_out, Xb, cst, WqT, WoT);

  // fused: qkv GEMM + bias + RoPE(LUT)/scale + head layout + V transpose
  k_gemm_qkv<<<dim3(3 * DM / 128, NB * SEQ / 128), 256, 0, stream>>>(
      Xb, WqT, b_qkv, cst, Qr, Kr, VtG);

  k_attn<<<1024, 512, 0, stream>>>(Qr, Kr, VtG, attn, ctx);

  k_gemm<0><<<dim3(DM / 128, NB * SEQ / 128), 256, 0, stream>>>(
      ctx, WoT, b_out, outp, NB * SEQ, DM, DM);
}